// Round 2
// baseline (70.254 us; speedup 1.0000x reference)
//
#include <hip/hip_runtime.h>

#define NBLOCKS 2048
#define NTHREADS 256

// Folded constants:
//   KTOT = sqrt(2) * 1.14136 * e^2     (sqrt(10) in emb cancels /sqrt(10) before relu;
//                                       relu is positively homogeneous so sqrt(2) folds in)
//   CL_l = PATH_C_l * 0.25 * (1/sqrt(10))   (w = h@W2/sqrt(16), node scale 1/sqrt(10))
#define KTOT 11.9269705f
#define CL0  0.04564355f
#define CL1  0.02635231f
#define CL2  0.02041241f
#define S3   1.7320508f
#define S5   2.2360680f

__global__ __launch_bounds__(NTHREADS) void edge_sum_kernel(
    const float* __restrict__ node_feats,
    const float* __restrict__ edge_vec,
    const float* __restrict__ W1,
    const float* __restrict__ W2,
    const int*   __restrict__ edge_src,
    float*       __restrict__ block_sums,
    int n_edges)
{
    // W1 [10][16] staged in LDS, row stride 5 float4 = 20 floats.
    // float4 type => 16B alignment guaranteed; pad cols 16..19 zero-filled so
    // no read can ever touch uninitialized LDS. Row stride 20 floats => row
    // starts hit banks {0,20,8,28,16,4,24,12,0,20}: <=2-way alias = free.
    __shared__ float4 sW1[10][5];
    float* sW1f = reinterpret_cast<float*>(sW1);
    const int tid = threadIdx.x;
    if (tid < 160) {
        sW1f[(tid >> 4) * 20 + (tid & 15)] = W1[tid];
    } else if (tid < 200) {
        const int i = tid - 160;
        sW1f[(i >> 2) * 20 + 16 + (i & 3)] = 0.0f;
    }
    __syncthreads();

    // W2 [16][3]: lane-uniform, fully unrolled constant indices -> registers.
    float w2r[16][3];
#pragma unroll
    for (int j = 0; j < 16; ++j)
#pragma unroll
        for (int l = 0; l < 3; ++l)
            w2r[j][l] = W2[j * 3 + l];

    float acc = 0.0f;
    const int stride = gridDim.x * blockDim.x;
    for (int e = blockIdx.x * blockDim.x + tid; e < n_edges; e += stride) {
        const float vx = edge_vec[3 * e + 0];
        const float vy = edge_vec[3 * e + 1];
        const float vz = edge_vec[3 * e + 2];
        const int   src = edge_src[e];

        const float r2 = vx * vx + vy * vy + vz * vz;
        const float rs = rsqrtf(fmaxf(r2, 1e-24f));
        const float r  = r2 * rs;                 // = sqrt(r2)
        const float x = vx * rs, y = vy * rs, z = vz * rs;

        // --- radial embedding: smooth_finite, at most 2 active bases ---
        // t = 11r, k0 = floor(t), frac in [0,1).
        // basis j=k0-1 (if 0<=j<=9): exp(-(1/(1+frac)+1/(1-frac))) = exp(-2/(1-frac^2))
        // basis j=k0   (if 0<=j<=9): exp(-(1/frac+1/(2-frac)))     = exp(-2/(frac(2-frac)))
        // Guard denominators: d <= 0.0226 -> exp(-2/d) <= 3e-39 ~ 0. No inf anywhere.
        const float t    = 11.0f * r;
        const int   k0   = (int)t;
        const float frac = t - (float)k0;
        float ea = 0.0f, eb = 0.0f;
        if (k0 >= 1 && k0 <= 10) {
            const float da = fmaf(-frac, frac, 1.0f);     // 1 - frac^2, in (0,1]
            if (da > 0.0226f) ea = KTOT * __expf(-2.0f / da);
        }
        if (k0 <= 9) {
            const float db = frac * (2.0f - frac);        // in [0,1)
            if (db > 0.0226f) eb = KTOT * __expf(-2.0f / db);
        }

        // --- h = relu(ea*W1[ra] + eb*W1[rb]); w = h@W2 (scales folded) ---
        const int ra = min(max(k0 - 1, 0), 9);
        const int rb = min(k0, 9);
        const float4* rowA = &sW1[ra][0];
        const float4* rowB = &sW1[rb][0];
        float wv0 = 0.0f, wv1 = 0.0f, wv2 = 0.0f;
#pragma unroll
        for (int q = 0; q < 4; ++q) {
            const float4 A = rowA[q];
            const float4 B = rowB[q];
            float h;
            h = fmaxf(fmaf(ea, A.x, eb * B.x), 0.0f);
            wv0 = fmaf(h, w2r[4 * q + 0][0], wv0); wv1 = fmaf(h, w2r[4 * q + 0][1], wv1); wv2 = fmaf(h, w2r[4 * q + 0][2], wv2);
            h = fmaxf(fmaf(ea, A.y, eb * B.y), 0.0f);
            wv0 = fmaf(h, w2r[4 * q + 1][0], wv0); wv1 = fmaf(h, w2r[4 * q + 1][1], wv1); wv2 = fmaf(h, w2r[4 * q + 1][2], wv2);
            h = fmaxf(fmaf(ea, A.z, eb * B.z), 0.0f);
            wv0 = fmaf(h, w2r[4 * q + 2][0], wv0); wv1 = fmaf(h, w2r[4 * q + 2][1], wv1); wv2 = fmaf(h, w2r[4 * q + 2][2], wv2);
            h = fmaxf(fmaf(ea, A.w, eb * B.w), 0.0f);
            wv0 = fmaf(h, w2r[4 * q + 3][0], wv0); wv1 = fmaf(h, w2r[4 * q + 3][1], wv1); wv2 = fmaf(h, w2r[4 * q + 3][2], wv2);
        }

        // --- spherical harmonics (component-normalized, lmax=2) dot f[src] ---
        const float* f = node_feats + 9 * src;
        const float f0 = f[0], f1 = f[1], f2 = f[2], f3 = f[3], f4 = f[4];
        const float f5 = f[5], f6 = f[6], f7 = f[7], f8 = f[8];

        const float dots0 = f0;
        const float dots1 = S3 * fmaf(f1, x, fmaf(f2, y, f3 * z));
        const float xx = x * x, yy = y * y, zz = z * z;
        const float sh20 = S5 * S3 * x * z;
        const float sh21 = S5 * S3 * x * y;
        const float sh22 = S5 * (yy - 0.5f * (xx + zz));
        const float sh23 = S5 * S3 * y * z;
        const float sh24 = S5 * 0.5f * S3 * (zz - xx);
        const float dots2 = fmaf(f4, sh20, fmaf(f5, sh21, fmaf(f6, sh22, fmaf(f7, sh23, f8 * sh24))));

        acc = fmaf(wv0, CL0 * dots0, acc);
        acc = fmaf(wv1, CL1 * dots1, acc);
        acc = fmaf(wv2, CL2 * dots2, acc);
    }

    // --- deterministic block reduction (xor butterfly: all reads in-range) ---
#pragma unroll
    for (int off = 1; off < 64; off <<= 1)
        acc += __shfl_xor(acc, off, 64);
    __shared__ float wsum[NTHREADS / 64];
    const int lane = tid & 63, wid = tid >> 6;
    if (lane == 0) wsum[wid] = acc;
    __syncthreads();
    if (tid == 0) {
        float s = 0.0f;
#pragma unroll
        for (int w = 0; w < NTHREADS / 64; ++w) s += wsum[w];
        block_sums[blockIdx.x] = s;
    }
}

__global__ __launch_bounds__(256) void final_reduce_kernel(
    const float* __restrict__ block_sums, float* __restrict__ out, int n)
{
    const int tid = threadIdx.x;
    float acc = 0.0f;
    for (int i = tid; i < n; i += 256) acc += block_sums[i];
#pragma unroll
    for (int off = 1; off < 64; off <<= 1)
        acc += __shfl_xor(acc, off, 64);
    __shared__ float wsum[4];
    if ((tid & 63) == 0) wsum[tid >> 6] = acc;
    __syncthreads();
    if (tid == 0) out[0] = wsum[0] + wsum[1] + wsum[2] + wsum[3];
}

extern "C" void kernel_launch(void* const* d_in, const int* in_sizes, int n_in,
                              void* d_out, int out_size, void* d_ws, size_t ws_size,
                              hipStream_t stream) {
    const float* node_feats = (const float*)d_in[0];
    const float* edge_vec   = (const float*)d_in[1];
    const float* W1         = (const float*)d_in[2];
    const float* W2         = (const float*)d_in[3];
    const int*   edge_src   = (const int*)d_in[4];
    // d_in[5] (edge_dst) intentionally unused: final output is the
    // order-independent sum over all edges; segment_sum().sum() == sum().
    const int n_edges = in_sizes[4];

    float* block_sums = (float*)d_ws; // NBLOCKS floats, fully rewritten every call

    edge_sum_kernel<<<NBLOCKS, NTHREADS, 0, stream>>>(
        node_feats, edge_vec, W1, W2, edge_src, block_sums, n_edges);
    final_reduce_kernel<<<1, 256, 0, stream>>>(block_sums, (float*)d_out, NBLOCKS);
}

// Round 3
// 60.939 us; speedup vs baseline: 1.1529x; 1.1529x over previous
//
#include <hip/hip_runtime.h>
#include <hip/hip_fp16.h>

#define NBLOCKS 2048
#define NTHREADS 256

// Folded constants:
//   KTOT = sqrt(2) * 1.14136 * e^2     (sqrt(10) in emb cancels /sqrt(10) before relu;
//                                       relu is positively homogeneous so sqrt(2) folds in)
//   CL_l = PATH_C_l * 0.25 * (1/sqrt(10))   (w = h@W2/sqrt(16), node scale 1/sqrt(10))
#define KTOT 11.9269705f
#define CL0  0.04564355f
#define CL1  0.02635231f
#define CL2  0.02041241f
#define S3   1.7320508f
#define S5   2.2360680f

// ---------- prep: pack node_feats [N][9] f32 -> [N][16] f16 (32B rows) ----------
__global__ __launch_bounds__(256) void pack_feats_kernel(
    const float* __restrict__ nf, unsigned* __restrict__ table, int n_nodes)
{
    const int n = blockIdx.x * 256 + threadIdx.x;
    if (n >= n_nodes) return;
    const float* f = nf + 9 * (size_t)n;
    unsigned u[5];
#pragma unroll
    for (int i = 0; i < 4; ++i) {
        __half2 h;
        h.x = __float2half_rn(f[2 * i]);
        h.y = __float2half_rn(f[2 * i + 1]);
        u[i] = *reinterpret_cast<unsigned*>(&h);
    }
    {
        __half2 h;
        h.x = __float2half_rn(f[8]);
        h.y = __float2half_rn(0.0f);
        u[4] = *reinterpret_cast<unsigned*>(&h);
    }
    *reinterpret_cast<uint4*>(table + 8 * (size_t)n) = make_uint4(u[0], u[1], u[2], u[3]);
    table[8 * (size_t)n + 4] = u[4];
    // halves 10..15 never read; left unwritten on purpose.
}

__device__ __forceinline__ float2 cvt2(unsigned u) {
    __half2 h = *reinterpret_cast<__half2*>(&u);
    return __half22float2(h);
}

// ---------- per-edge term (fully inlined) ----------
__device__ __forceinline__ float edge_term(
    float vx, float vy, float vz, int src,
    const unsigned* __restrict__ table,
    const float4* __restrict__ sW1v,
    const float (&w2r)[16][3])
{
    // gather: one 64B-line access (rows are 32B-aligned), issued first
    const uint4    g0 = *reinterpret_cast<const uint4*>(table + 8 * (size_t)src);
    const unsigned g1 = table[8 * (size_t)src + 4];

    const float r2 = fmaf(vx, vx, fmaf(vy, vy, vz * vz));
    const float rs = rsqrtf(fmaxf(r2, 1e-24f));
    const float r  = r2 * rs;
    const float x = vx * rs, y = vy * rs, z = vz * rs;

    // radial: smooth_finite, <=2 active bases, no inf anywhere
    const float t    = 11.0f * r;
    const int   k0   = (int)t;
    const float frac = t - (float)k0;
    float ea = 0.0f, eb = 0.0f;
    if (k0 >= 1 && k0 <= 10) {
        const float da = fmaf(-frac, frac, 1.0f);   // 1 - frac^2
        if (da > 0.0226f) ea = KTOT * __expf(-2.0f / da);
    }
    if (k0 <= 9) {
        const float db = frac * (2.0f - frac);
        if (db > 0.0226f) eb = KTOT * __expf(-2.0f / db);
    }

    const int ra = min(max(k0 - 1, 0), 9);
    const int rb = min(k0, 9);
    const float4* rowA = sW1v + ra * 5;
    const float4* rowB = sW1v + rb * 5;
    float wv0 = 0.0f, wv1 = 0.0f, wv2 = 0.0f;
#pragma unroll
    for (int q = 0; q < 4; ++q) {
        const float4 A = rowA[q];
        const float4 B = rowB[q];
        float h;
        h = fmaxf(fmaf(ea, A.x, eb * B.x), 0.0f);
        wv0 = fmaf(h, w2r[4 * q + 0][0], wv0); wv1 = fmaf(h, w2r[4 * q + 0][1], wv1); wv2 = fmaf(h, w2r[4 * q + 0][2], wv2);
        h = fmaxf(fmaf(ea, A.y, eb * B.y), 0.0f);
        wv0 = fmaf(h, w2r[4 * q + 1][0], wv0); wv1 = fmaf(h, w2r[4 * q + 1][1], wv1); wv2 = fmaf(h, w2r[4 * q + 1][2], wv2);
        h = fmaxf(fmaf(ea, A.z, eb * B.z), 0.0f);
        wv0 = fmaf(h, w2r[4 * q + 2][0], wv0); wv1 = fmaf(h, w2r[4 * q + 2][1], wv1); wv2 = fmaf(h, w2r[4 * q + 2][2], wv2);
        h = fmaxf(fmaf(ea, A.w, eb * B.w), 0.0f);
        wv0 = fmaf(h, w2r[4 * q + 3][0], wv0); wv1 = fmaf(h, w2r[4 * q + 3][1], wv1); wv2 = fmaf(h, w2r[4 * q + 3][2], wv2);
    }

    // gathered feats fp16 -> f32
    const float2 f01 = cvt2(g0.x);
    const float2 f23 = cvt2(g0.y);
    const float2 f45 = cvt2(g0.z);
    const float2 f67 = cvt2(g0.w);
    const float2 f8_ = cvt2(g1);

    const float dots0 = f01.x;
    const float dots1 = S3 * fmaf(f01.y, x, fmaf(f23.x, y, f23.y * z));
    const float xx = x * x, yy = y * y, zz = z * z;
    const float sh20 = S5 * S3 * x * z;
    const float sh21 = S5 * S3 * x * y;
    const float sh22 = S5 * (yy - 0.5f * (xx + zz));
    const float sh23 = S5 * S3 * y * z;
    const float sh24 = S5 * 0.5f * S3 * (zz - xx);
    const float dots2 = fmaf(f45.x, sh20, fmaf(f45.y, sh21,
                        fmaf(f67.x, sh22, fmaf(f67.y, sh23, f8_.x * sh24))));

    float term;
    term = wv0 * (CL0 * dots0);
    term = fmaf(wv1, CL1 * dots1, term);
    term = fmaf(wv2, CL2 * dots2, term);
    return term;
}

// ---------- main: 4 edges per thread per iteration ----------
__global__ __launch_bounds__(NTHREADS) void edge_sum_packed(
    const float4* __restrict__ ev4,      // edge_vec viewed as float4
    const int4*   __restrict__ src4,     // edge_src viewed as int4
    const unsigned* __restrict__ table,  // packed fp16 feats
    const float*  __restrict__ W1,
    const float*  __restrict__ W2,
    float*        __restrict__ block_sums,
    int n_edges)
{
    __shared__ float4 sW1[10][5];
    float* sW1f = reinterpret_cast<float*>(sW1);
    const int tid = threadIdx.x;
    if (tid < 160) {
        sW1f[(tid >> 4) * 20 + (tid & 15)] = W1[tid];
    } else if (tid < 200) {
        const int i = tid - 160;
        sW1f[(i >> 2) * 20 + 16 + (i & 3)] = 0.0f;
    }
    __syncthreads();

    float w2r[16][3];
#pragma unroll
    for (int j = 0; j < 16; ++j)
#pragma unroll
        for (int l = 0; l < 3; ++l)
            w2r[j][l] = W2[j * 3 + l];

    const float4* sW1v = &sW1[0][0];
    float acc = 0.0f;
    const int n_groups = (n_edges + 3) >> 2;
    const int stride = gridDim.x * blockDim.x;
    for (int g = blockIdx.x * blockDim.x + tid; g < n_groups; g += stride) {
        const int e0 = g << 2;
        if (e0 + 3 < n_edges) {
            const float4 a = ev4[3 * (size_t)g + 0];
            const float4 b = ev4[3 * (size_t)g + 1];
            const float4 c = ev4[3 * (size_t)g + 2];
            const int4   s = src4[g];
            acc += edge_term(a.x, a.y, a.z, s.x, table, sW1v, w2r);
            acc += edge_term(a.w, b.x, b.y, s.y, table, sW1v, w2r);
            acc += edge_term(b.z, b.w, c.x, s.z, table, sW1v, w2r);
            acc += edge_term(c.y, c.z, c.w, s.w, table, sW1v, w2r);
        } else {
            const float* evf  = reinterpret_cast<const float*>(ev4);
            const int*   srci = reinterpret_cast<const int*>(src4);
            for (int e = e0; e < n_edges; ++e)
                acc += edge_term(evf[3 * (size_t)e], evf[3 * (size_t)e + 1],
                                 evf[3 * (size_t)e + 2], srci[e], table, sW1v, w2r);
        }
    }

    // deterministic block reduction
#pragma unroll
    for (int off = 1; off < 64; off <<= 1)
        acc += __shfl_xor(acc, off, 64);
    __shared__ float wsum[NTHREADS / 64];
    const int lane = tid & 63, wid = tid >> 6;
    if (lane == 0) wsum[wid] = acc;
    __syncthreads();
    if (tid == 0) {
        float ssum = 0.0f;
#pragma unroll
        for (int w = 0; w < NTHREADS / 64; ++w) ssum += wsum[w];
        block_sums[blockIdx.x] = ssum;
    }
}

// ---------- fallback (round-2 proven path, f32 scalar gather) ----------
__global__ __launch_bounds__(NTHREADS) void edge_sum_fallback(
    const float* __restrict__ node_feats,
    const float* __restrict__ edge_vec,
    const float* __restrict__ W1,
    const float* __restrict__ W2,
    const int*   __restrict__ edge_src,
    float*       __restrict__ block_sums,
    int n_edges)
{
    __shared__ float4 sW1[10][5];
    float* sW1f = reinterpret_cast<float*>(sW1);
    const int tid = threadIdx.x;
    if (tid < 160) {
        sW1f[(tid >> 4) * 20 + (tid & 15)] = W1[tid];
    } else if (tid < 200) {
        const int i = tid - 160;
        sW1f[(i >> 2) * 20 + 16 + (i & 3)] = 0.0f;
    }
    __syncthreads();

    float w2r[16][3];
#pragma unroll
    for (int j = 0; j < 16; ++j)
#pragma unroll
        for (int l = 0; l < 3; ++l)
            w2r[j][l] = W2[j * 3 + l];

    float acc = 0.0f;
    const int stride = gridDim.x * blockDim.x;
    for (int e = blockIdx.x * blockDim.x + tid; e < n_edges; e += stride) {
        const float vx = edge_vec[3 * (size_t)e + 0];
        const float vy = edge_vec[3 * (size_t)e + 1];
        const float vz = edge_vec[3 * (size_t)e + 2];
        const int   src = edge_src[e];
        const float r2 = fmaf(vx, vx, fmaf(vy, vy, vz * vz));
        const float rs = rsqrtf(fmaxf(r2, 1e-24f));
        const float r  = r2 * rs;
        const float x = vx * rs, y = vy * rs, z = vz * rs;
        const float t    = 11.0f * r;
        const int   k0   = (int)t;
        const float frac = t - (float)k0;
        float ea = 0.0f, eb = 0.0f;
        if (k0 >= 1 && k0 <= 10) {
            const float da = fmaf(-frac, frac, 1.0f);
            if (da > 0.0226f) ea = KTOT * __expf(-2.0f / da);
        }
        if (k0 <= 9) {
            const float db = frac * (2.0f - frac);
            if (db > 0.0226f) eb = KTOT * __expf(-2.0f / db);
        }
        const int ra = min(max(k0 - 1, 0), 9);
        const int rb = min(k0, 9);
        const float4* rowA = &sW1[ra][0];
        const float4* rowB = &sW1[rb][0];
        float wv0 = 0.0f, wv1 = 0.0f, wv2 = 0.0f;
#pragma unroll
        for (int q = 0; q < 4; ++q) {
            const float4 A = rowA[q];
            const float4 B = rowB[q];
            float h;
            h = fmaxf(fmaf(ea, A.x, eb * B.x), 0.0f);
            wv0 = fmaf(h, w2r[4 * q + 0][0], wv0); wv1 = fmaf(h, w2r[4 * q + 0][1], wv1); wv2 = fmaf(h, w2r[4 * q + 0][2], wv2);
            h = fmaxf(fmaf(ea, A.y, eb * B.y), 0.0f);
            wv0 = fmaf(h, w2r[4 * q + 1][0], wv0); wv1 = fmaf(h, w2r[4 * q + 1][1], wv1); wv2 = fmaf(h, w2r[4 * q + 1][2], wv2);
            h = fmaxf(fmaf(ea, A.z, eb * B.z), 0.0f);
            wv0 = fmaf(h, w2r[4 * q + 2][0], wv0); wv1 = fmaf(h, w2r[4 * q + 2][1], wv1); wv2 = fmaf(h, w2r[4 * q + 2][2], wv2);
            h = fmaxf(fmaf(ea, A.w, eb * B.w), 0.0f);
            wv0 = fmaf(h, w2r[4 * q + 3][0], wv0); wv1 = fmaf(h, w2r[4 * q + 3][1], wv1); wv2 = fmaf(h, w2r[4 * q + 3][2], wv2);
        }
        const float* f = node_feats + 9 * (size_t)src;
        const float f0 = f[0], f1 = f[1], f2 = f[2], f3 = f[3], f4 = f[4];
        const float f5 = f[5], f6 = f[6], f7 = f[7], f8 = f[8];
        const float dots0 = f0;
        const float dots1 = S3 * fmaf(f1, x, fmaf(f2, y, f3 * z));
        const float xx = x * x, yy = y * y, zz = z * z;
        const float sh20 = S5 * S3 * x * z;
        const float sh21 = S5 * S3 * x * y;
        const float sh22 = S5 * (yy - 0.5f * (xx + zz));
        const float sh23 = S5 * S3 * y * z;
        const float sh24 = S5 * 0.5f * S3 * (zz - xx);
        const float dots2 = fmaf(f4, sh20, fmaf(f5, sh21, fmaf(f6, sh22, fmaf(f7, sh23, f8 * sh24))));
        acc = fmaf(wv0, CL0 * dots0, acc);
        acc = fmaf(wv1, CL1 * dots1, acc);
        acc = fmaf(wv2, CL2 * dots2, acc);
    }
#pragma unroll
    for (int off = 1; off < 64; off <<= 1)
        acc += __shfl_xor(acc, off, 64);
    __shared__ float wsum[NTHREADS / 64];
    const int lane = tid & 63, wid = tid >> 6;
    if (lane == 0) wsum[wid] = acc;
    __syncthreads();
    if (tid == 0) {
        float ssum = 0.0f;
#pragma unroll
        for (int w = 0; w < NTHREADS / 64; ++w) ssum += wsum[w];
        block_sums[blockIdx.x] = ssum;
    }
}

__global__ __launch_bounds__(256) void final_reduce_kernel(
    const float* __restrict__ block_sums, float* __restrict__ out, int n)
{
    const int tid = threadIdx.x;
    float acc = 0.0f;
    for (int i = tid; i < n; i += 256) acc += block_sums[i];
#pragma unroll
    for (int off = 1; off < 64; off <<= 1)
        acc += __shfl_xor(acc, off, 64);
    __shared__ float wsum[4];
    if ((tid & 63) == 0) wsum[tid >> 6] = acc;
    __syncthreads();
    if (tid == 0) out[0] = wsum[0] + wsum[1] + wsum[2] + wsum[3];
}

extern "C" void kernel_launch(void* const* d_in, const int* in_sizes, int n_in,
                              void* d_out, int out_size, void* d_ws, size_t ws_size,
                              hipStream_t stream) {
    const float* node_feats = (const float*)d_in[0];
    const float* edge_vec   = (const float*)d_in[1];
    const float* W1         = (const float*)d_in[2];
    const float* W2         = (const float*)d_in[3];
    const int*   edge_src   = (const int*)d_in[4];
    // d_in[5] (edge_dst) unused: segment_sum().sum() == plain sum over edges.
    const int n_edges = in_sizes[4];
    const int n_nodes = in_sizes[0] / 9;

    float* block_sums = (float*)d_ws;                 // NBLOCKS floats
    const size_t need = 8192 + (size_t)n_nodes * 32;  // table after 8KB

    if (ws_size >= need) {
        unsigned* table = (unsigned*)((char*)d_ws + 8192);
        pack_feats_kernel<<<(n_nodes + 255) / 256, 256, 0, stream>>>(
            node_feats, table, n_nodes);
        edge_sum_packed<<<NBLOCKS, NTHREADS, 0, stream>>>(
            (const float4*)edge_vec, (const int4*)edge_src, table,
            W1, W2, block_sums, n_edges);
    } else {
        edge_sum_fallback<<<NBLOCKS, NTHREADS, 0, stream>>>(
            node_feats, edge_vec, W1, W2, edge_src, block_sums, n_edges);
    }
    final_reduce_kernel<<<1, 256, 0, stream>>>(block_sums, (float*)d_out, NBLOCKS);
}